// Round 4
// baseline (194.712 us; speedup 1.0000x reference)
//
#include <hip/hip_runtime.h>
#include <hip/hip_bf16.h>
#include <math.h>

#define Bsz 2048
#define Lsz 1024
#define SW  8   // waves (batches) per block; grid = 2048/8 = 256 blocks = 1/CU

__device__ __forceinline__ float __rlf(float v, int i) {
    return __int_as_float(__builtin_amdgcn_readlane(__float_as_int(v), i));
}

// Single fused kernel: every block redundantly builds the 64-token tables
// (registers + readlane broadcasts only — no LDS-latency chains), then runs
// 8 independent batch scans (one per wave) against LDS-resident Gc/P.
__global__ __launch_bounds__(512) void fused_kernel(
    const int* __restrict__ seq,
    const float* __restrict__ embed_W, const float* __restrict__ ff_w1, const float* __restrict__ ff_b1,
    const float* __restrict__ ff_w2, const float* __restrict__ ff_b2, const float* __restrict__ ln_g,
    const float* __restrict__ ln_b, const float* __restrict__ gate_w1, const float* __restrict__ gate_b1,
    const float* __restrict__ gate_w2, const float* __restrict__ gate_b2, const float* __restrict__ read_w,
    const float* __restrict__ read_b, const float* __restrict__ out_w, const float* __restrict__ out_b,
    float* __restrict__ out)
{
    __shared__ int   toks[SW][1136];     // [0..63] dummy pad; [64+t] = seq token t
    __shared__ float ldsGc[65 * 64];     // c_v * G[v][:]; row 64 = zeros (dummy token)
    __shared__ float ldsP[64 * 64];      // P[v][:] = h_v @ (read_w @ out_w)
    __shared__ float ldsHW[64 * 65 * 2]; // slot (j*65+c): {.x = h[c][j], .y = Wc[j][c]}
    __shared__ float ldsg[64];           // g per token
    __shared__ float ldscinv[64];        // 1/c = denom/g per token

    const int tid  = threadIdx.x;
    const int wave = tid >> 6;
    const int lane = tid & 63;
    const int b    = blockIdx.x * SW + wave;

    // stage this wave's token row into registers early (overlaps phase 1)
    const int4* tsrc = (const int4*)(seq + (size_t)b * Lsz);
    const int4 tv0 = tsrc[lane], tv1 = tsrc[64 + lane], tv2 = tsrc[128 + lane], tv3 = tsrc[192 + lane];

    // ================= PHASE 1: build tables (wave w owns tokens 8w..8w+7) ===
    const int v0 = wave << 3;
    float e[8];
    #pragma unroll
    for (int k = 0; k < 8; ++k) e[k] = embed_W[((v0 + k) << 6) + lane];

    // z = relu(E @ ff_w1 + b1): lane j holds z_j (za) and z_{j+64} (zb)
    float za[8], zb[8];
    {
        const float b1a = ff_b1[lane], b1b = ff_b1[64 + lane];
        #pragma unroll
        for (int k = 0; k < 8; ++k) { za[k] = b1a; zb[k] = b1b; }
    }
    #pragma unroll 16
    for (int i = 0; i < 64; ++i) {
        const float w1a = ff_w1[i * 128 + lane];
        const float w1b = ff_w1[i * 128 + 64 + lane];
        #pragma unroll
        for (int k = 0; k < 8; ++k) {
            const float ei = __rlf(e[k], i);
            za[k] = fmaf(ei, w1a, za[k]);
            zb[k] = fmaf(ei, w1b, zb[k]);
        }
    }
    #pragma unroll
    for (int k = 0; k < 8; ++k) { za[k] = fmaxf(za[k], 0.0f); zb[k] = fmaxf(zb[k], 0.0f); }

    // x = E + z @ ff_w2 + b2 : lane i holds x[v][i]
    float h[8];
    {
        const float b2l = ff_b2[lane];
        #pragma unroll
        for (int k = 0; k < 8; ++k) h[k] = e[k] + b2l;
    }
    #pragma unroll 16
    for (int j = 0; j < 64; ++j) {
        const float w2a = ff_w2[j * 64 + lane];
        const float w2b = ff_w2[(j + 64) * 64 + lane];
        #pragma unroll
        for (int k = 0; k < 8; ++k) {
            h[k] = fmaf(__rlf(za[k], j), w2a, h[k]);
            h[k] = fmaf(__rlf(zb[k], j), w2b, h[k]);
        }
    }

    // park token row in LDS now (global loads long since landed)
    {
        int* T = toks[wave];
        if (lane < 16) ((int4*)T)[lane] = make_int4(64, 64, 64, 64);
        int4* dst = (int4*)(T + 64);
        dst[lane] = tv0; dst[64 + lane] = tv1; dst[128 + lane] = tv2; dst[192 + lane] = tv3;
    }

    // LayerNorm + denom; write h^T part of HW
    float cL[8];   // c = g/denom (finished after gate)
    {
        const float lg = ln_g[lane], lb = ln_b[lane];
        #pragma unroll
        for (int k = 0; k < 8; ++k) {
            float mu = h[k];
            #pragma unroll
            for (int off = 32; off > 0; off >>= 1) mu += __shfl_xor(mu, off);
            mu *= (1.0f / 64.0f);
            const float dd = h[k] - mu;
            float var = dd * dd;
            #pragma unroll
            for (int off = 32; off > 0; off >>= 1) var += __shfl_xor(var, off);
            var *= (1.0f / 64.0f);
            const float rstd = rsqrtf(var + 1e-5f);
            const float hv = fmaf(dd * rstd, lg, lb);
            h[k] = hv;
            ldsHW[(lane * 65 + (v0 + k)) * 2] = hv;     // h[v][lane] at slot (lane*65+v).x
            float dn = hv * hv;
            #pragma unroll
            for (int off = 32; off > 0; off >>= 1) dn += __shfl_xor(dn, off);
            cL[k] = dn + 1e-6f;                          // denom for now
        }
    }

    // gate: g = sigmoid(relu(h@gw1+gb1)@gw2+gb2); all lanes mirror m=lane&15
    {
        const int m = lane & 15;
        const float gb1 = gate_b1[m], gw2v = gate_w2[m], gb2 = gate_b2[0];
        #pragma unroll
        for (int k = 0; k < 8; ++k) {
            float u = gb1;
            #pragma unroll 16
            for (int i = 0; i < 64; ++i) u = fmaf(__rlf(h[k], i), gate_w1[i * 16 + m], u);
            u = fmaxf(u, 0.0f) * gw2v;
            u += __shfl_xor(u, 1); u += __shfl_xor(u, 2);
            u += __shfl_xor(u, 4); u += __shfl_xor(u, 8);
            const float g = 1.0f / (1.0f + __expf(-(u + gb2)));
            if (lane == 0) { ldsg[v0 + k] = g; ldscinv[v0 + k] = cL[k] / g; }
            cL[k] = g / cL[k];                           // c = g/denom
        }
    }

    // Wc rows j = v0+k : Wc[j][lane] = sum_m read_w[j][m] * out_w[m][lane]
    {
        float rw[8], wc[8];
        #pragma unroll
        for (int k = 0; k < 8; ++k) { rw[k] = read_w[((v0 + k) << 6) + lane]; wc[k] = 0.0f; }
        #pragma unroll 16
        for (int mm = 0; mm < 64; ++mm) {
            const float ow = out_w[(mm << 6) + lane];
            #pragma unroll
            for (int k = 0; k < 8; ++k) wc[k] = fmaf(__rlf(rw[k], mm), ow, wc[k]);
        }
        #pragma unroll
        for (int k = 0; k < 8; ++k) ldsHW[((v0 + k) * 65 + lane) * 2 + 1] = wc[k];
    }
    if (tid < 64) ldsGc[4096 + tid] = 0.0f;   // dummy-token Gc row

    __syncthreads();

    // rows: Gc[v][lane] and P[v][lane] via one ds_read_b64 per j
    {
        float accG[8] = {0,0,0,0,0,0,0,0}, accP[8] = {0,0,0,0,0,0,0,0};
        #pragma unroll 16
        for (int j = 0; j < 64; ++j) {
            const float2 hw = *(const float2*)&ldsHW[(j * 65 + lane) * 2]; // {h[lane][j], Wc[j][lane]}
            #pragma unroll
            for (int k = 0; k < 8; ++k) {
                const float hv = __rlf(h[k], j);
                accG[k] = fmaf(hv, hw.x, accG[k]);
                accP[k] = fmaf(hv, hw.y, accP[k]);
            }
        }
        #pragma unroll
        for (int k = 0; k < 8; ++k) {
            const int v = v0 + k;
            ldsGc[(v << 6) + lane] = cL[k] * accG[k];
            ldsP [(v << 6) + lane] = accP[k];
        }
    }

    // bc = read_b @ out_w + out_b (per wave, cheap)
    float bc = out_b[lane];
    {
        const float rb = read_b[lane];
        #pragma unroll 16
        for (int j = 0; j < 64; ++j) bc = fmaf(__rlf(rb, j), out_w[(j << 6) + lane], bc);
    }

    __syncthreads();

    // ================= PHASE 2: scan (one wave per batch) ====================
    int* T = toks[wave];
    const int tokL = T[1087];   // query token
    T[1087] = 64;               // pad step t=1023 -> dummy (Gc row 64 = 0)
    float D = ldsGc[(tokL << 6) + lane] * ldscinv[tokL];   // D_v = G[tokL][v]
    float u = 0.0f;

    int   tkA[16], tkB[16];
    float gcA[16], gcB[16];

    int tokvA = T[1072 + lane];
    #pragma unroll
    for (int k = 0; k < 16; ++k) {
        tkA[k] = __builtin_amdgcn_readlane(tokvA, 15 - k);
        gcA[k] = ldsGc[(tkA[k] << 6) + lane];
    }
    int tokvB = T[1056 + lane];

    for (int t0 = 1023; t0 > 0; t0 -= 32) {
        #pragma unroll
        for (int k = 0; k < 16; ++k) {
            tkB[k] = __builtin_amdgcn_readlane(tokvB, 15 - k);
            gcB[k] = ldsGc[(tkB[k] << 6) + lane];
        }
        const int tokvA2 = T[t0 + 17 + lane];
        #pragma unroll
        for (int k = 0; k < 16; ++k) {
            const int tok = tkA[k];
            const float d = __rlf(D, tok);
            u += (lane == tok) ? d : 0.0f;
            D = fmaf(-d, gcA[k], D);
        }
        #pragma unroll
        for (int k = 0; k < 16; ++k) {
            tkA[k] = __builtin_amdgcn_readlane(tokvA2, 15 - k);
            gcA[k] = ldsGc[(tkA[k] << 6) + lane];
        }
        const int tokvB2 = T[t0 + 1 + lane];
        #pragma unroll
        for (int k = 0; k < 16; ++k) {
            const int tok = tkB[k];
            const float d = __rlf(D, tok);
            u += (lane == tok) ? d : 0.0f;
            D = fmaf(-d, gcB[k], D);
        }
        tokvB = tokvB2;
    }

    // epilogue: s = g*u ; logits = s @ P + bc (all wave-local via readlane)
    const float s = u * ldsg[lane];
    float acc = bc;
    #pragma unroll 16
    for (int v = 0; v < 64; ++v)
        acc = fmaf(__rlf(s, v), ldsP[(v << 6) + lane], acc);
    out[(size_t)b * 64 + lane] = acc;
}

extern "C" void kernel_launch(void* const* d_in, const int* in_sizes, int n_in,
                              void* d_out, int out_size, void* d_ws, size_t ws_size,
                              hipStream_t stream) {
    const int*   seq     = (const int*)  d_in[0];
    const float* embed_W = (const float*)d_in[1];
    const float* ff_w1   = (const float*)d_in[2];
    const float* ff_b1   = (const float*)d_in[3];
    const float* ff_w2   = (const float*)d_in[4];
    const float* ff_b2   = (const float*)d_in[5];
    const float* ln_g    = (const float*)d_in[6];
    const float* ln_b    = (const float*)d_in[7];
    const float* gate_w1 = (const float*)d_in[8];
    const float* gate_b1 = (const float*)d_in[9];
    const float* gate_w2 = (const float*)d_in[10];
    const float* gate_b2 = (const float*)d_in[11];
    const float* read_w  = (const float*)d_in[12];
    const float* read_b  = (const float*)d_in[13];
    const float* out_w   = (const float*)d_in[14];
    const float* out_b   = (const float*)d_in[15];
    float* out = (float*)d_out;

    hipLaunchKernelGGL(fused_kernel, dim3(Bsz / SW), dim3(SW * 64), 0, stream,
                       seq, embed_W, ff_w1, ff_b1, ff_w2, ff_b2, ln_g, ln_b,
                       gate_w1, gate_b1, gate_w2, gate_b2, read_w, read_b,
                       out_w, out_b, out);
}

// Round 5
// 134.584 us; speedup vs baseline: 1.4468x; 1.4468x over previous
//
#include <hip/hip_runtime.h>
#include <hip/hip_bf16.h>
#include <math.h>

#define Bsz 2048
#define Lsz 1024
#define SW  8   // waves (batches) per scan block

// ws layout (float offsets)
#define OFF_G   0        // Gram               64x64
#define OFF_GC  4096     // c_v * G[v][:]      64x64
#define OFF_P   8192     // g_v * (h_v @ (read_w@out_w))  64x64  (g pre-folded)
#define OFF_WC  12288    // read_w @ out_w     64x64
#define OFF_GV  16384    // g per token        64
#define OFF_C   16448    // c per token        64
#define OFF_BC  16512    // read_b@out_w+out_b 64

__device__ __forceinline__ float __rlf(float v, int i) {
    return __int_as_float(__builtin_amdgcn_readlane(__float_as_int(v), i));
}

// ---------------- prep1: per-token h/g/c (blocks 0..63), Wc rows (64..127), bc (128)
__global__ __launch_bounds__(128) void prep1_kernel(
    const float* __restrict__ embed_W, const float* __restrict__ ff_w1, const float* __restrict__ ff_b1,
    const float* __restrict__ ff_w2, const float* __restrict__ ff_b2, const float* __restrict__ ln_g,
    const float* __restrict__ ln_b, const float* __restrict__ gate_w1, const float* __restrict__ gate_b1,
    const float* __restrict__ gate_w2, const float* __restrict__ gate_b2, const float* __restrict__ read_w,
    const float* __restrict__ read_b, const float* __restrict__ out_w, const float* __restrict__ out_b,
    float* __restrict__ ws)
{
    const int tid = threadIdx.x;
    const int blk = blockIdx.x;
    if (blk < 64) {
        const int v = blk;
        __shared__ float z[128];
        __shared__ float hsh[64];
        const float* Ev = embed_W + (v << 6);
        float a = ff_b1[tid];
        #pragma unroll
        for (int i = 0; i < 64; ++i) a = fmaf(Ev[i], ff_w1[i * 128 + tid], a);
        z[tid] = fmaxf(a, 0.0f);
        __syncthreads();
        if (tid < 64) {   // wave 0 only
            float x = Ev[tid] + ff_b2[tid];
            #pragma unroll
            for (int j = 0; j < 128; ++j) x = fmaf(z[j], ff_w2[j * 64 + tid], x);
            float mu = x;
            #pragma unroll
            for (int off = 32; off > 0; off >>= 1) mu += __shfl_xor(mu, off);
            mu *= (1.0f / 64.0f);
            const float dd = x - mu;
            float var = dd * dd;
            #pragma unroll
            for (int off = 32; off > 0; off >>= 1) var += __shfl_xor(var, off);
            var *= (1.0f / 64.0f);
            const float rstd = rsqrtf(var + 1e-5f);
            const float hv = fmaf(dd * rstd, ln_g[tid], ln_b[tid]);
            ws[OFF_G + 0] = ws[OFF_G + 0];   // no-op keep
            ws[/*table reuse*/ OFF_WC + 4096 + 0] = ws[OFF_WC + 4096 + 0]; // (unused)
            hsh[tid] = hv;
            float dn = hv * hv;
            #pragma unroll
            for (int off = 32; off > 0; off >>= 1) dn += __shfl_xor(dn, off);
            dn += 1e-6f;
            float a2 = 0.0f;
            if (tid < 16) {
                float um = gate_b1[tid];
                #pragma unroll
                for (int i = 0; i < 64; ++i) um = fmaf(hsh[i], gate_w1[i * 16 + tid], um);
                a2 = fmaxf(um, 0.0f) * gate_w2[tid];
            }
            #pragma unroll
            for (int off = 8; off > 0; off >>= 1) a2 += __shfl_xor(a2, off);
            // store h into a temp region: reuse OFF_G row as staging for prep2? No —
            // store the h table into its own slot: use OFF_G for table temporarily.
            ws[OFF_G + (v << 6) + tid] = hv;   // prep2 reads this as the h table
            if (tid == 0) {
                a2 += gate_b2[0];
                const float g = 1.0f / (1.0f + expf(-a2));
                ws[OFF_GV + v] = g;
                ws[OFF_C + v]  = g / dn;
            }
        }
    } else if (blk < 128) {
        const int j = blk - 64;
        if (tid < 64) {
            float a = 0.0f;
            #pragma unroll
            for (int m = 0; m < 64; ++m) a = fmaf(read_w[(j << 6) + m], out_w[(m << 6) + tid], a);
            ws[OFF_WC + (j << 6) + tid] = a;
        }
    } else {
        if (tid < 64) {
            float a = out_b[tid];
            #pragma unroll
            for (int jj = 0; jj < 64; ++jj) a = fmaf(read_b[jj], out_w[(jj << 6) + tid], a);
            ws[OFF_BC + tid] = a;
        }
    }
}

// ---------------- prep2: Gram/Gc rows (blocks 0..63) — overwrites OFF_G in place
// with the true Gram; P rows (64..127) with g pre-folded.
// NOTE: OFF_G holds the h table on entry (written by prep1). Each Gram block
// first copies the table to LDS, syncs, then overwrites only its own row.
__global__ __launch_bounds__(64) void prep2_kernel(float* __restrict__ ws)
{
    const int tid = threadIdx.x;
    const int blk = blockIdx.x;
    __shared__ float tT[65 * 64];   // tT[j*65+w] = h[w][j] (padded)
    for (int idx = tid; idx < 4096; idx += 64) {
        const int w = idx >> 6, j = idx & 63;
        tT[j * 65 + w] = ws[OFF_G + idx];   // h table
    }
    __syncthreads();
    if (blk < 64) {
        const int v = blk;
        const float cv = ws[OFF_C + v];
        float a = 0.0f;
        #pragma unroll
        for (int j = 0; j < 64; ++j) a = fmaf(tT[j * 65 + v], tT[j * 65 + tid], a);
        ws[OFF_G  + (v << 6) + tid] = a;      // true Gram row v (safe: LDS copy taken)
        ws[OFF_GC + (v << 6) + tid] = cv * a;
    } else {
        const int v = blk - 64;
        const float gv = ws[OFF_GV + v];
        float a = 0.0f;
        #pragma unroll
        for (int j = 0; j < 64; ++j)
            a = fmaf(tT[j * 65 + v], ws[OFF_WC + (j << 6) + tid], a);
        ws[OFF_P + (v << 6) + tid] = gv * a;  // g folded into P
    }
}

// ---------------- scan: one wave per batch; packed tokens (4/int, scalar-pipe
// extraction), A/B 16-step gc pipeline, 1 ds_read_b32 per step.
__global__ __launch_bounds__(SW * 64) void scan_kernel(const int* __restrict__ seq,
                                                       const float* __restrict__ ws,
                                                       float* __restrict__ out)
{
    __shared__ float ldsGc[65 * 64];          // rows 0..63 real; row 64 zeros (dummy tok 64)
    __shared__ float ldsPg[4096];             // g_v * P rows
    __shared__ int   pk[SW][16 + 256 + 64];   // packed tokens; P=pk+16; front pad=dummy
    __shared__ float ldsbc[64];

    const int tid  = threadIdx.x;
    const int wave = tid >> 6;
    const int lane = tid & 63;

    {
        const float4* srcGc = (const float4*)(ws + OFF_GC);
        const float4* srcP  = (const float4*)(ws + OFF_P);
        float4* dGc = (float4*)ldsGc;
        float4* dP  = (float4*)ldsPg;
        for (int i = tid; i < 1024; i += SW * 64) { dGc[i] = srcGc[i]; dP[i] = srcP[i]; }
    }
    if (tid < 64) {
        ldsGc[4096 + tid] = 0.0f;
        ldsbc[tid] = ws[OFF_BC + tid];
    }
    const int b = blockIdx.x * SW + wave;
    int* P = pk[wave] + 16;
    {
        const int4* src = (const int4*)(seq + (size_t)b * Lsz);
        #pragma unroll
        for (int i = 0; i < 4; ++i) {
            const int4 tv = src[i * 64 + lane];
            P[i * 64 + lane] = tv.x | (tv.y << 8) | (tv.z << 16) | (tv.w << 24);
        }
        if (lane < 16) pk[wave][lane] = 0x40404040;   // front pad: token 64 (dummy)
    }
    __syncthreads();

    // last word holds steps 1020..1023; step 1023 is the query -> replace with dummy 64
    const int lastw = P[255];
    const int tokL  = (lastw >> 24) & 0xFF;
    if (lane == 0) P[255] = (lastw & 0x00FFFFFF) | (64 << 24);

    float D = ws[OFF_G + (tokL << 6) + lane];   // D_v = e_v . q  (L2-hot global read)
    float u = 0.0f;

    int   tkA[16], tkB[16];
    float gcA[16], gcB[16];

    // prologue for t0 = 1023: tokv covers words (t0>>2)-7 .. (t0>>2) = 248..255
    int tokv = P[248 + lane];
    #pragma unroll
    for (int j = 0; j < 4; ++j) {
        const int w = __builtin_amdgcn_readlane(tokv, 7 - j);
        tkA[4 * j + 0] = (w >> 24) & 0xFF;
        tkA[4 * j + 1] = (w >> 16) & 0xFF;
        tkA[4 * j + 2] = (w >>  8) & 0xFF;
        tkA[4 * j + 3] =  w        & 0xFF;
    }
    #pragma unroll
    for (int k = 0; k < 16; ++k) gcA[k] = ldsGc[(tkA[k] << 6) + lane];

    for (int t0 = 1023; t0 > 0; t0 -= 32) {
        // token words for NEXT iteration (distance: consumed after compute A)
        const int tokvN = P[(((t0 - 32) >> 2) - 7) + lane];
        // B tokens (words wbase..wbase+3 = tokv lanes 3..0, descending) + gc issue
        #pragma unroll
        for (int j = 0; j < 4; ++j) {
            const int w = __builtin_amdgcn_readlane(tokv, 3 - j);
            tkB[4 * j + 0] = (w >> 24) & 0xFF;
            tkB[4 * j + 1] = (w >> 16) & 0xFF;
            tkB[4 * j + 2] = (w >>  8) & 0xFF;
            tkB[4 * j + 3] =  w        & 0xFF;
        }
        #pragma unroll
        for (int k = 0; k < 16; ++k) gcB[k] = ldsGc[(tkB[k] << 6) + lane];
        // compute A: steps t0 .. t0-15
        #pragma unroll
        for (int k = 0; k < 16; ++k) {
            const int tok = tkA[k];
            const float d = __rlf(D, tok);
            u += (lane == tok) ? d : 0.0f;
            D = fmaf(-d, gcA[k], D);
        }
        // next-iter A tokens (tokvN lanes 7..4) + gc issue
        #pragma unroll
        for (int j = 0; j < 4; ++j) {
            const int w = __builtin_amdgcn_readlane(tokvN, 7 - j);
            tkA[4 * j + 0] = (w >> 24) & 0xFF;
            tkA[4 * j + 1] = (w >> 16) & 0xFF;
            tkA[4 * j + 2] = (w >>  8) & 0xFF;
            tkA[4 * j + 3] =  w        & 0xFF;
        }
        #pragma unroll
        for (int k = 0; k < 16; ++k) gcA[k] = ldsGc[(tkA[k] << 6) + lane];
        // compute B: steps t0-16 .. t0-31
        #pragma unroll
        for (int k = 0; k < 16; ++k) {
            const int tok = tkB[k];
            const float d = __rlf(D, tok);
            u += (lane == tok) ? d : 0.0f;
            D = fmaf(-d, gcB[k], D);
        }
        tokv = tokvN;
    }

    // epilogue: logits = (g .* u) @ P + bc, with g pre-folded into ldsPg
    float acc = ldsbc[lane];
    #pragma unroll 16
    for (int v = 0; v < 64; ++v)
        acc = fmaf(__rlf(u, v), ldsPg[(v << 6) + lane], acc);
    out[(size_t)b * 64 + lane] = acc;
}

extern "C" void kernel_launch(void* const* d_in, const int* in_sizes, int n_in,
                              void* d_out, int out_size, void* d_ws, size_t ws_size,
                              hipStream_t stream) {
    const int*   seq     = (const int*)  d_in[0];
    const float* embed_W = (const float*)d_in[1];
    const float* ff_w1   = (const float*)d_in[2];
    const float* ff_b1   = (const float*)d_in[3];
    const float* ff_w2   = (const float*)d_in[4];
    const float* ff_b2   = (const float*)d_in[5];
    const float* ln_g    = (const float*)d_in[6];
    const float* ln_b    = (const float*)d_in[7];
    const float* gate_w1 = (const float*)d_in[8];
    const float* gate_b1 = (const float*)d_in[9];
    const float* gate_w2 = (const float*)d_in[10];
    const float* gate_b2 = (const float*)d_in[11];
    const float* read_w  = (const float*)d_in[12];
    const float* read_b  = (const float*)d_in[13];
    const float* out_w   = (const float*)d_in[14];
    const float* out_b   = (const float*)d_in[15];
    float* ws  = (float*)d_ws;
    float* out = (float*)d_out;

    hipLaunchKernelGGL(prep1_kernel, dim3(129), dim3(128), 0, stream,
                       embed_W, ff_w1, ff_b1, ff_w2, ff_b2, ln_g, ln_b,
                       gate_w1, gate_b1, gate_w2, gate_b2, read_w, read_b,
                       out_w, out_b, ws);
    hipLaunchKernelGGL(prep2_kernel, dim3(128), dim3(64), 0, stream, ws);
    hipLaunchKernelGGL(scan_kernel, dim3(Bsz / SW), dim3(SW * 64), 0, stream,
                       seq, ws, out);
}